// Round 3
// baseline (445.630 us; speedup 1.0000x reference)
//
#include <hip/hip_runtime.h>
#include <hip/hip_bf16.h>

#define B_ 4
#define S_ 4096
#define E_ 1024
#define D_ 128

typedef unsigned short u16;
typedef __bf16 bf16x8 __attribute__((ext_vector_type(8)));
typedef unsigned short u16x8 __attribute__((ext_vector_type(8)));
typedef float f32x4 __attribute__((ext_vector_type(4)));

__device__ inline u16 f2bf(float f) {
    __bf16 h = (__bf16)f;
    return __builtin_bit_cast(u16, h);
}

// ---------------------------------------------------------------------------
// Kernel 0: W [E,D] f32 -> Wt [3][D][E] bf16 (proj 0 pre-scaled by 1/sqrt(D))
// ---------------------------------------------------------------------------
__global__ __launch_bounds__(256) void wt_kernel(const float* __restrict__ Wq,
                                                 const float* __restrict__ Wk,
                                                 const float* __restrict__ Wv,
                                                 u16* __restrict__ Wt) {
    int tid = blockIdx.x * 256 + threadIdx.x;       // 0 .. 3*131072-1
    int w = tid >> 17;                               // 131072 = 2^17
    int rem = tid & 131071;
    int d = rem >> 10;
    int e = rem & 1023;
    const float* W = (w == 0) ? Wq : ((w == 1) ? Wk : Wv);
    float v = W[e * D_ + d];
    if (w == 0) v *= 0.08838834764831845f;           // 1/sqrt(128)
    Wt[tid] = f2bf(v);
}

// ---------------------------------------------------------------------------
// Kernel 1: QKV projection GEMM. M=16384, K=1024, N=128 per proj.
// Block: 256 thr (4 waves), 64 rows x 128 cols per block. grid (256, 3).
// proj 0 -> q bf16 [B,S,D] (scaled), proj 1 -> k bf16 [B,S,D],
// proj 2 -> vT bf16 [B,D,S].
// MFMA 16x16x32: A row = lane&15, k = (lane>>4)*8+j ; B col = lane&15,
// k = (lane>>4)*8+j ; C/D col = lane&15, row = (lane>>4)*4+reg.
// ---------------------------------------------------------------------------
__global__ __launch_bounds__(256) void qkv_kernel(const float* __restrict__ x,
                                                  const u16* __restrict__ Wt,
                                                  u16* __restrict__ q,
                                                  u16* __restrict__ k,
                                                  u16* __restrict__ vT) {
    const int proj = blockIdx.y;
    const int mtile = blockIdx.x * 64;
    const int wv = threadIdx.x >> 6;
    const int l = threadIdx.x & 63;
    const int g = l >> 4;
    const int c = l & 15;

    const int rowA = mtile + wv * 16 + c;
    const float* xp = x + (size_t)rowA * E_ + g * 8;
    const u16* wp = Wt + (size_t)proj * (D_ * E_) + (size_t)c * E_ + g * 8;

    f32x4 acc[8] = {};

    for (int ks = 0; ks < E_ / 32; ks++) {
        union { bf16x8 v; __bf16 e[8]; } av;
        const float4 x0 = *(const float4*)(xp + ks * 32);
        const float4 x1 = *(const float4*)(xp + ks * 32 + 4);
        av.e[0] = (__bf16)x0.x; av.e[1] = (__bf16)x0.y;
        av.e[2] = (__bf16)x0.z; av.e[3] = (__bf16)x0.w;
        av.e[4] = (__bf16)x1.x; av.e[5] = (__bf16)x1.y;
        av.e[6] = (__bf16)x1.z; av.e[7] = (__bf16)x1.w;
#pragma unroll
        for (int ct = 0; ct < 8; ct++) {
            bf16x8 bw = *(const bf16x8*)(wp + (size_t)ct * 16 * E_ + ks * 32);
            acc[ct] = __builtin_amdgcn_mfma_f32_16x16x32_bf16(av.v, bw, acc[ct], 0, 0, 0);
        }
    }

    if (proj < 2) {
        u16* dst = proj ? k : q;
#pragma unroll
        for (int ct = 0; ct < 8; ct++) {
#pragma unroll
            for (int j = 0; j < 4; j++) {
                int row = mtile + wv * 16 + g * 4 + j;
                dst[(size_t)row * D_ + ct * 16 + c] = f2bf(acc[ct][j]);
            }
        }
    } else {
        int srow = mtile + wv * 16 + g * 4;
        int b = srow >> 12;
        int s = srow & 4095;
#pragma unroll
        for (int ct = 0; ct < 8; ct++) {
            ushort4 pk;
            pk.x = f2bf(acc[ct][0]);
            pk.y = f2bf(acc[ct][1]);
            pk.z = f2bf(acc[ct][2]);
            pk.w = f2bf(acc[ct][3]);
            *(ushort4*)(vT + ((size_t)(b * D_ + ct * 16 + c)) * S_ + s) = pk;
        }
    }
}

// ---------------------------------------------------------------------------
// Kernel 2: flash attention. grid (S/64, B), 256 thr (4 waves).
// Each wave: 16 q rows, loops KV in blocks of 64.
// P transposed via per-wave XOR-swizzled LDS (16 rows x 128B).
// Output written as FLOAT32 (reference output dtype is f32; harness reads
// d_out as float*). r1/r2 failure was bf16-packed writes into an f32 buffer.
// ---------------------------------------------------------------------------
__global__ __launch_bounds__(256) void attn_kernel(const u16* __restrict__ q,
                                                   const u16* __restrict__ k,
                                                   const u16* __restrict__ vT,
                                                   float* __restrict__ out) {
    const int b = blockIdx.y;
    const int qt = blockIdx.x;
    const int wv = threadIdx.x >> 6;
    const int l = threadIdx.x & 63;
    const int g = l >> 4;
    const int c = l & 15;
    const int qrow0 = qt * 64 + wv * 16;   // within batch

    __shared__ __align__(16) u16 plds[4][1024];   // 2KB per wave
    u16* pw = &plds[wv][0];

    // Q fragments, hoisted (scaled already, via Wq)
    bf16x8 aq[4];
    const u16* qp = q + ((size_t)(b * S_ + qrow0 + c)) * D_ + g * 8;
#pragma unroll
    for (int ks = 0; ks < 4; ks++) aq[ks] = *(const bf16x8*)(qp + ks * 32);

    f32x4 o[8] = {};
    float m[4], ll[4];
#pragma unroll
    for (int j = 0; j < 4; j++) { m[j] = -1e30f; ll[j] = 0.0f; }

    const u16* kb = k + (size_t)b * S_ * D_;
    const u16* vb = vT + (size_t)b * D_ * S_;

    for (int kt = 0; kt < S_ / 64; kt++) {
        const int kvbase = kt * 64;

        // ---- S = Q K^T : 4 tiles of 16 kv-cols, K-dim 128 (4 MFMA steps) ----
        f32x4 s[4] = {};
#pragma unroll
        for (int t = 0; t < 4; t++) {
            const u16* kp = kb + ((size_t)(kvbase + t * 16 + c)) * D_ + g * 8;
#pragma unroll
            for (int ks = 0; ks < 4; ks++) {
                bf16x8 bk = *(const bf16x8*)(kp + ks * 32);
                s[t] = __builtin_amdgcn_mfma_f32_16x16x32_bf16(aq[ks], bk, s[t], 0, 0, 0);
            }
        }

        // ---- online softmax (rows live in 16-lane groups) ----
        float pv[4][4];
#pragma unroll
        for (int j = 0; j < 4; j++) {
            float tm = fmaxf(fmaxf(s[0][j], s[1][j]), fmaxf(s[2][j], s[3][j]));
            tm = fmaxf(tm, __shfl_xor(tm, 1));
            tm = fmaxf(tm, __shfl_xor(tm, 2));
            tm = fmaxf(tm, __shfl_xor(tm, 4));
            tm = fmaxf(tm, __shfl_xor(tm, 8));
            float mn = fmaxf(m[j], tm);
            float alpha = exp2f((m[j] - mn) * 1.44269504f);
            float rs = 0.f;
#pragma unroll
            for (int t = 0; t < 4; t++) {
                float p = exp2f((s[t][j] - mn) * 1.44269504f);
                pv[t][j] = p;
                rs += p;
            }
            rs += __shfl_xor(rs, 1);
            rs += __shfl_xor(rs, 2);
            rs += __shfl_xor(rs, 4);
            rs += __shfl_xor(rs, 8);
            ll[j] = ll[j] * alpha + rs;
            m[j] = mn;
#pragma unroll
            for (int ct = 0; ct < 8; ct++) o[ct][j] *= alpha;
        }

        // ---- P -> LDS, XOR-swizzled so A-frag reads are ~conflict-free ----
#pragma unroll
        for (int t = 0; t < 4; t++) {
#pragma unroll
            for (int j = 0; j < 4; j++) {
                int r = g * 4 + j;
                int cf = t * 16 + c;
                int slot = (cf >> 3) ^ ((r & 7) ^ ((r & 8) >> 2));
                pw[r * 64 + slot * 8 + (cf & 7)] = f2bf(pv[t][j]);
            }
        }
        __syncthreads();   // order LDS writes vs vector reads (provably safe)

        // ---- PV: O += P[16,64] * V[64,128] ----
#pragma unroll
        for (int st = 0; st < 2; st++) {
            int rho = c;
            int sigma = g + st * 4;
            int slot = sigma ^ ((rho & 7) ^ ((rho & 8) >> 2));
            u16x8 praw = *(const u16x8*)(pw + rho * 64 + slot * 8);
            bf16x8 pa = __builtin_bit_cast(bf16x8, praw);
#pragma unroll
            for (int ct = 0; ct < 8; ct++) {
                const u16* vp = vb + ((size_t)(ct * 16 + c)) * S_ + kvbase + st * 32 + g * 8;
                bf16x8 bv = *(const bf16x8*)vp;
                o[ct] = __builtin_amdgcn_mfma_f32_16x16x32_bf16(pa, bv, o[ct], 0, 0, 0);
            }
        }
        __syncthreads();   // keep next iteration's P-writes off these reads
    }

    // ---- epilogue: divide by l, store FLOAT32 ----
    float rinv[4];
#pragma unroll
    for (int j = 0; j < 4; j++) rinv[j] = 1.0f / ll[j];
#pragma unroll
    for (int ct = 0; ct < 8; ct++) {
#pragma unroll
        for (int j = 0; j < 4; j++) {
            int row = b * S_ + qt * 64 + wv * 16 + g * 4 + j;
            out[(size_t)row * D_ + ct * 16 + c] = o[ct][j] * rinv[j];
        }
    }
}

extern "C" void kernel_launch(void* const* d_in, const int* in_sizes, int n_in,
                              void* d_out, int out_size, void* d_ws, size_t ws_size,
                              hipStream_t stream) {
    const float* x  = (const float*)d_in[0];
    const float* Wq = (const float*)d_in[1];
    const float* Wk = (const float*)d_in[2];
    const float* Wv = (const float*)d_in[3];
    float* out = (float*)d_out;   // reference output dtype is float32

    // workspace layout (bytes): q 4MB | k 4MB | vT 4MB | Wt 768KB
    u16* q  = (u16*)d_ws;
    u16* k  = q  + (size_t)B_ * S_ * D_;
    u16* vT = k  + (size_t)B_ * S_ * D_;
    u16* Wt = vT + (size_t)B_ * S_ * D_;

    wt_kernel<<<(3 * D_ * E_) / 256, 256, 0, stream>>>(Wq, Wk, Wv, Wt);
    qkv_kernel<<<dim3((B_ * S_) / 64, 3), 256, 0, stream>>>(x, Wt, q, k, vT);
    attn_kernel<<<dim3(S_ / 64, B_), 256, 0, stream>>>(q, k, vT, out);
}

// Round 4
// 361.926 us; speedup vs baseline: 1.2313x; 1.2313x over previous
//
#include <hip/hip_runtime.h>
#include <hip/hip_bf16.h>

#define B_ 4
#define S_ 4096
#define E_ 1024
#define D_ 128

typedef unsigned short u16;
typedef __bf16 bf16x8 __attribute__((ext_vector_type(8)));
typedef unsigned short u16x8 __attribute__((ext_vector_type(8)));
typedef float f32x4 __attribute__((ext_vector_type(4)));

__device__ inline u16 f2bf(float f) {
    __bf16 h = (__bf16)f;
    return __builtin_bit_cast(u16, h);
}

// ---------------------------------------------------------------------------
// Kernel 0: W [E,D] f32 -> Wt [3][D][E] bf16 (proj 0 pre-scaled by 1/sqrt(D))
// ---------------------------------------------------------------------------
__global__ __launch_bounds__(256) void wt_kernel(const float* __restrict__ Wq,
                                                 const float* __restrict__ Wk,
                                                 const float* __restrict__ Wv,
                                                 u16* __restrict__ Wt) {
    int tid = blockIdx.x * 256 + threadIdx.x;       // 0 .. 3*131072-1
    int w = tid >> 17;                               // 131072 = 2^17
    int rem = tid & 131071;
    int d = rem >> 10;
    int e = rem & 1023;
    const float* W = (w == 0) ? Wq : ((w == 1) ? Wk : Wv);
    float v = W[e * D_ + d];
    if (w == 0) v *= 0.08838834764831845f;           // 1/sqrt(128)
    Wt[tid] = f2bf(v);
}

// ---------------------------------------------------------------------------
// Kernel 1: FUSED QKV projection. Each block: 16 rows x 384 cols (q|k|v),
// reading its x rows ONCE (64 MB total vs 192 MB for 3 passes).
// 4 waves: wave wv covers output cols [wv*96, wv*96+96) = 6 MFMA col-tiles.
// Grid 1024 blocks -> 4 blocks/CU, ~60 VGPR -> high occupancy.
// ---------------------------------------------------------------------------
__global__ __launch_bounds__(256) void qkv_fused(const float* __restrict__ x,
                                                 const u16* __restrict__ Wt,
                                                 u16* __restrict__ q,
                                                 u16* __restrict__ k,
                                                 u16* __restrict__ vT) {
    const int mtile = blockIdx.x * 16;
    const int wv = threadIdx.x >> 6;
    const int l = threadIdx.x & 63;
    const int g = l >> 4;
    const int c = l & 15;

    const int rowA = mtile + c;
    const float* xp = x + (size_t)rowA * E_ + g * 8;

    // B pointers per col-tile (proj/dcol compile-time after unroll)
    const u16* wp[6];
#pragma unroll
    for (int ct = 0; ct < 6; ct++) {
        int gc = wv * 96 + ct * 16;          // global output col (tile base)
        int proj = gc >> 7;
        int dcol = gc & 127;
        wp[ct] = Wt + (size_t)proj * (D_ * E_) + (size_t)(dcol + c) * E_ + g * 8;
    }

    f32x4 acc[6] = {};

    for (int ks = 0; ks < E_ / 32; ks++) {
        union { bf16x8 v; __bf16 e[8]; } av;
        const float4 x0 = *(const float4*)(xp + ks * 32);
        const float4 x1 = *(const float4*)(xp + ks * 32 + 4);
        av.e[0] = (__bf16)x0.x; av.e[1] = (__bf16)x0.y;
        av.e[2] = (__bf16)x0.z; av.e[3] = (__bf16)x0.w;
        av.e[4] = (__bf16)x1.x; av.e[5] = (__bf16)x1.y;
        av.e[6] = (__bf16)x1.z; av.e[7] = (__bf16)x1.w;
#pragma unroll
        for (int ct = 0; ct < 6; ct++) {
            bf16x8 bw = *(const bf16x8*)(wp[ct] + ks * 32);
            acc[ct] = __builtin_amdgcn_mfma_f32_16x16x32_bf16(av.v, bw, acc[ct], 0, 0, 0);
        }
    }

#pragma unroll
    for (int ct = 0; ct < 6; ct++) {
        int gc = wv * 96 + ct * 16;
        int proj = gc >> 7;
        int dcol = gc & 127;
        if (proj < 2) {
            u16* dst = proj ? k : q;
#pragma unroll
            for (int j = 0; j < 4; j++) {
                int row = mtile + g * 4 + j;
                dst[(size_t)row * D_ + dcol + c] = f2bf(acc[ct][j]);
            }
        } else {
            int srow = mtile + g * 4;
            int b = srow >> 12;
            int s = srow & 4095;
            ushort4 pk;
            pk.x = f2bf(acc[ct][0]);
            pk.y = f2bf(acc[ct][1]);
            pk.z = f2bf(acc[ct][2]);
            pk.w = f2bf(acc[ct][3]);
            *(ushort4*)(vT + ((size_t)(b * D_ + dcol + c)) * S_ + s) = pk;
        }
    }
}

// ---------------------------------------------------------------------------
// Kernel 2: flash attention, KV-split across the block's 4 waves.
// Grid 1024 (1D, XCD-chunk swizzled: each XCD serves exactly 1 batch so
// its 2MB KV fits the 4MB per-XCD L2). Block: 16 q-rows; wave wv processes
// KV tiles [wv*16, wv*16+16) of 64 rows each, keeping private (o,m,l).
// LDS combine at the end (2 barriers). plds P-buffer is unioned with the
// 32KB combine buffer; no in-loop barriers (plds is wave-private).
// ---------------------------------------------------------------------------
__global__ __launch_bounds__(256, 4) void attn_kernel(const u16* __restrict__ q,
                                                      const u16* __restrict__ k,
                                                      const u16* __restrict__ vT,
                                                      float* __restrict__ out) {
    // bijective XCD-chunk swizzle (nwg=1024, 8 XCDs, chunk=128)
    int bid = blockIdx.x;
    int sw = (bid & 7) * 128 + (bid >> 3);
    const int b = sw >> 8;          // batch 0..3 (2 XCDs per batch)
    const int qt = sw & 255;        // q-tile 0..255 (16 rows)
    const int wv = threadIdx.x >> 6;
    const int l = threadIdx.x & 63;
    const int g = l >> 4;
    const int c = l & 15;
    const int qrow0 = qt * 16;

    __shared__ __align__(16) char smem[4 * 16 * 128 * 4];   // 32KB: plds then co
    __shared__ float cm[4][16], cl[4][16];
    u16* pw = (u16*)(smem + wv * 2048);      // per-wave 2KB P buffer
    float* co = (float*)smem;                 // combine buffer (after barrier)

    // Q fragments, hoisted (scaled already, via Wq)
    bf16x8 aq[4];
    const u16* qp = q + ((size_t)(b * S_ + qrow0 + c)) * D_ + g * 8;
#pragma unroll
    for (int ks = 0; ks < 4; ks++) aq[ks] = *(const bf16x8*)(qp + ks * 32);

    f32x4 o[8] = {};
    float m[4], ll[4];
#pragma unroll
    for (int j = 0; j < 4; j++) { m[j] = -1e30f; ll[j] = 0.0f; }

    const u16* kb = k + (size_t)b * S_ * D_;
    const u16* vb = vT + (size_t)b * D_ * S_;

    for (int kt = wv * 16; kt < wv * 16 + 16; kt++) {
        const int kvbase = kt * 64;

        // ---- S = Q K^T : 4 tiles of 16 kv-cols, K-dim 128 (4 MFMA steps) ----
        f32x4 s[4] = {};
#pragma unroll
        for (int t = 0; t < 4; t++) {
            const u16* kp = kb + ((size_t)(kvbase + t * 16 + c)) * D_ + g * 8;
#pragma unroll
            for (int ks = 0; ks < 4; ks++) {
                bf16x8 bk = *(const bf16x8*)(kp + ks * 32);
                s[t] = __builtin_amdgcn_mfma_f32_16x16x32_bf16(aq[ks], bk, s[t], 0, 0, 0);
            }
        }

        // ---- online softmax (rows live in 16-lane groups) ----
        float pv[4][4];
#pragma unroll
        for (int j = 0; j < 4; j++) {
            float tm = fmaxf(fmaxf(s[0][j], s[1][j]), fmaxf(s[2][j], s[3][j]));
            tm = fmaxf(tm, __shfl_xor(tm, 1));
            tm = fmaxf(tm, __shfl_xor(tm, 2));
            tm = fmaxf(tm, __shfl_xor(tm, 4));
            tm = fmaxf(tm, __shfl_xor(tm, 8));
            float mn = fmaxf(m[j], tm);
            float alpha = exp2f((m[j] - mn) * 1.44269504f);
            float rs = 0.f;
#pragma unroll
            for (int t = 0; t < 4; t++) {
                float p = exp2f((s[t][j] - mn) * 1.44269504f);
                pv[t][j] = p;
                rs += p;
            }
            rs += __shfl_xor(rs, 1);
            rs += __shfl_xor(rs, 2);
            rs += __shfl_xor(rs, 4);
            rs += __shfl_xor(rs, 8);
            ll[j] = ll[j] * alpha + rs;
            m[j] = mn;
#pragma unroll
            for (int ct = 0; ct < 8; ct++) o[ct][j] *= alpha;
        }

        // ---- P -> LDS (wave-private), XOR-swizzled ----
#pragma unroll
        for (int t = 0; t < 4; t++) {
#pragma unroll
            for (int j = 0; j < 4; j++) {
                int r = g * 4 + j;
                int cf = t * 16 + c;
                int slot = (cf >> 3) ^ ((r & 7) ^ ((r & 8) >> 2));
                pw[r * 64 + slot * 8 + (cf & 7)] = f2bf(pv[t][j]);
            }
        }

        // ---- PV: O += P[16,64] * V[64,128] ----
#pragma unroll
        for (int st = 0; st < 2; st++) {
            int rho = c;
            int sigma = g + st * 4;
            int slot = sigma ^ ((rho & 7) ^ ((rho & 8) >> 2));
            u16x8 praw = *(const u16x8*)(pw + rho * 64 + slot * 8);
            bf16x8 pa = __builtin_bit_cast(bf16x8, praw);
#pragma unroll
            for (int ct = 0; ct < 8; ct++) {
                const u16* vp = vb + ((size_t)(ct * 16 + c)) * S_ + kvbase + st * 32 + g * 8;
                bf16x8 bv = *(const bf16x8*)vp;
                o[ct] = __builtin_amdgcn_mfma_f32_16x16x32_bf16(pa, bv, o[ct], 0, 0, 0);
            }
        }
    }

    // ---- combine partials across the 4 waves ----
    __syncthreads();   // all waves done with pw before co overwrites it
#pragma unroll
    for (int ct = 0; ct < 8; ct++) {
#pragma unroll
        for (int j = 0; j < 4; j++) {
            co[(wv * 16 + g * 4 + j) * 128 + ct * 16 + c] = o[ct][j];
        }
    }
    if (c == 0) {
#pragma unroll
        for (int j = 0; j < 4; j++) {
            cm[wv][g * 4 + j] = m[j];
            cl[wv][g * 4 + j] = ll[j];
        }
    }
    __syncthreads();

    // 256 threads cover 16 rows x 128 cols: thread -> (row r, 8 cols at cb)
    {
        int r = threadIdx.x >> 4;
        int cb = (threadIdx.x & 15) * 8;
        float M = fmaxf(fmaxf(cm[0][r], cm[1][r]), fmaxf(cm[2][r], cm[3][r]));
        float ew[4];
        float Lsum = 0.f;
#pragma unroll
        for (int w = 0; w < 4; w++) {
            ew[w] = exp2f((cm[w][r] - M) * 1.44269504f);
            Lsum += cl[w][r] * ew[w];
        }
        float rL = 1.0f / Lsum;
        float res[8];
#pragma unroll
        for (int i = 0; i < 8; i++) {
            float a = 0.f;
#pragma unroll
            for (int w = 0; w < 4; w++) a += co[(w * 16 + r) * 128 + cb + i] * ew[w];
            res[i] = a * rL;
        }
        float* op = out + ((size_t)(b * S_ + qrow0 + r)) * D_ + cb;
        float4 r0 = make_float4(res[0], res[1], res[2], res[3]);
        float4 r1 = make_float4(res[4], res[5], res[6], res[7]);
        *(float4*)op = r0;
        *(float4*)(op + 4) = r1;
    }
}

extern "C" void kernel_launch(void* const* d_in, const int* in_sizes, int n_in,
                              void* d_out, int out_size, void* d_ws, size_t ws_size,
                              hipStream_t stream) {
    const float* x  = (const float*)d_in[0];
    const float* Wq = (const float*)d_in[1];
    const float* Wk = (const float*)d_in[2];
    const float* Wv = (const float*)d_in[3];
    float* out = (float*)d_out;   // reference output dtype is float32

    // workspace layout (bytes): q 4MB | k 4MB | vT 4MB | Wt 768KB
    u16* q  = (u16*)d_ws;
    u16* k  = q  + (size_t)B_ * S_ * D_;
    u16* vT = k  + (size_t)B_ * S_ * D_;
    u16* Wt = vT + (size_t)B_ * S_ * D_;

    wt_kernel<<<(3 * D_ * E_) / 256, 256, 0, stream>>>(Wq, Wk, Wv, Wt);
    qkv_fused<<<(B_ * S_) / 16, 256, 0, stream>>>(x, Wt, q, k, vT);
    attn_kernel<<<(B_ * S_) / 16, 256, 0, stream>>>(q, k, vT, out);
}